// Round 4
// baseline (44459.772 us; speedup 1.0000x reference)
//
#include <hip/hip_runtime.h>
#include <math.h>

constexpr int Bsz = 256, Tsz = 1024, Isz = 64, Hsz = 256, Osz = 8;
constexpr int NB = 4;     // batch rows per group
constexpr int NG = 4;     // column-split wgs per batch group
constexpr int K  = Hsz + Isz;   // 320
constexpr int SPIN_CAP = 1 << 14;   // bounded spin: wrong-fast beats hang

#define SCOPE_AGENT __HIP_MEMORY_SCOPE_AGENT

// FMA over one float4 of comb against 4 weight regs
#define FMA4(vv, warr, base)                      \
  acc[b] = fmaf(vv.x, warr[(base)+0], acc[b]);    \
  acc[b] = fmaf(vv.y, warr[(base)+1], acc[b]);    \
  acc[b] = fmaf(vv.z, warr[(base)+2], acc[b]);    \
  acc[b] = fmaf(vv.w, warr[(base)+3], acc[b]);

__global__ __launch_bounds__(256, 1) void lstm_ws_kernel(
    const float* __restrict__ x,
    const float* __restrict__ W_f, const float* __restrict__ b_f,
    const float* __restrict__ W_i, const float* __restrict__ b_i,
    const float* __restrict__ W_c, const float* __restrict__ b_c,
    const float* __restrict__ W_o, const float* __restrict__ b_o,
    const float* __restrict__ W_ho, const float* __restrict__ b_ho,
    float* __restrict__ out, int* __restrict__ cnt, float* __restrict__ Hbuf)
{
    __shared__ float comb[NB][K];       // [h(256) | x(64)] per batch row
    __shared__ float gat[4][NB][64];    // gate exchange within wg

    const int j  = threadIdx.x;
    const int g  = blockIdx.x >> 6;     // column-group 0..3
    const int bg = blockIdx.x & 63;     // batch-group 0..63 (consecutive blocks -> spread XCDs)
    const int b0 = bg * NB;
    const int q  = j >> 6;              // gate index (f,i,c,o)
    const int m  = j & 63;              // col within my 64-col h slice
    const int hcol = g * 64 + m;        // column of W_q this thread owns

    const float* Wq  = (q == 0) ? W_f : (q == 1) ? W_i : (q == 2) ? W_c : W_o;
    const float* bqp = (q == 0) ? b_f : (q == 1) ? b_i : (q == 2) ? b_c : b_o;
    const float bias = bqp[hcol];

    // ---- weight-stationary preload into VGPRs (done once; zero traffic after) ----
    float wOwn[64], wOth[192], wX[64];
    #pragma unroll
    for (int kk = 0; kk < 64; ++kk) wOwn[kk] = Wq[(g * 64 + kk) * Hsz + hcol];
    #pragma unroll
    for (int r = 1; r < 4; ++r) {
        const int kb = ((g + r) & 3) * 64;
        #pragma unroll
        for (int kk = 0; kk < 64; ++kk)
            wOth[(r - 1) * 64 + kk] = Wq[(kb + kk) * Hsz + hcol];
    }
    #pragma unroll
    for (int kk = 0; kk < 64; ++kk) wX[kk] = Wq[(Hsz + kk) * Hsz + hcol];

    // ---- init: h(-1)=0, stage x(0) ----
    #pragma unroll
    for (int b = 0; b < NB; ++b) comb[b][j] = 0.0f;          // cols 0..255
    comb[j >> 6][Hsz + m] = x[((size_t)(b0 + (j >> 6)) * Tsz + 0) * Isz + m];
    float cstate = 0.0f;    // c for (b=j>>6, col g*64+m)
    __syncthreads();

    int* mycnt = cnt + bg;

    for (int t = 0; t < Tsz; ++t) {
        float acc[NB];
        #pragma unroll
        for (int b = 0; b < NB; ++b) acc[b] = bias;

        // ---- phase A: locally-known k ranges (own h slice + x) — runs before the spin ----
        const int ob = g * 64;
        #pragma unroll
        for (int c4 = 0; c4 < 16; ++c4) {
            #pragma unroll
            for (int b = 0; b < NB; ++b) {
                const float4 v = *(const float4*)&comb[b][ob + c4 * 4];
                FMA4(v, wOwn, c4 * 4)
            }
        }
        #pragma unroll
        for (int c4 = 0; c4 < 16; ++c4) {
            #pragma unroll
            for (int b = 0; b < NB; ++b) {
                const float4 v = *(const float4*)&comb[b][Hsz + c4 * 4];
                FMA4(v, wX, c4 * 4)
            }
        }

        // ---- wait for peers' h(t-1) (ACQUIRE: invalidates stale L1/L2), refill 192 cols ----
        if (t) {
            if (j == 0) {
                int it = 0;
                while (__hip_atomic_load(mycnt, __ATOMIC_ACQUIRE, SCOPE_AGENT) < 4 * t
                       && it++ < SPIN_CAP)
                    __builtin_amdgcn_s_sleep(8);
            }
            __syncthreads();
            {
                const int b = j >> 6;
                if ((m >> 4) != g) {     // skip own slice (already in comb)
                    const float* src = Hbuf + ((((size_t)((t - 1) & 1)) * 64 + bg) * 4 + b) * 256;
                    const int col = 4 * m;
                    const float a0 = __hip_atomic_load(src + col + 0, __ATOMIC_RELAXED, SCOPE_AGENT);
                    const float a1 = __hip_atomic_load(src + col + 1, __ATOMIC_RELAXED, SCOPE_AGENT);
                    const float a2 = __hip_atomic_load(src + col + 2, __ATOMIC_RELAXED, SCOPE_AGENT);
                    const float a3 = __hip_atomic_load(src + col + 3, __ATOMIC_RELAXED, SCOPE_AGENT);
                    comb[b][col + 0] = a0; comb[b][col + 1] = a1;
                    comb[b][col + 2] = a2; comb[b][col + 3] = a3;
                }
            }
            __syncthreads();
        }

        // ---- phase B: the other 3 h-slices (rotated so array indices stay static) ----
        #pragma unroll
        for (int r = 0; r < 3; ++r) {
            const int kb = ((g + r + 1) & 3) * 64;
            #pragma unroll
            for (int c4 = 0; c4 < 16; ++c4) {
                #pragma unroll
                for (int b = 0; b < NB; ++b) {
                    const float4 v = *(const float4*)&comb[b][kb + c4 * 4];
                    FMA4(v, wOth, r * 64 + c4 * 4)
                }
            }
        }

        // ---- prefetch x(t+1) (consumed after the final barrier) ----
        float xv;
        {
            const int tt = (t + 1 < Tsz) ? t + 1 : t;
            xv = x[((size_t)(b0 + (j >> 6)) * Tsz + tt) * Isz + m];
        }

        // ---- gate exchange + cell update ----
        #pragma unroll
        for (int b = 0; b < NB; ++b) gat[q][b][m] = acc[b];
        __syncthreads();
        {
            const int b = j >> 6;
            const float gf = gat[0][b][m], gi = gat[1][b][m];
            const float gc = gat[2][b][m], go = gat[3][b][m];
            const float f  = 1.0f / (1.0f + expf(-gf));
            const float ii = 1.0f / (1.0f + expf(-gi));
            const float ch = tanhf(gc);
            const float oo = 1.0f / (1.0f + expf(-go));
            cstate = f * cstate + ii * ch;
            const float h = oo * tanhf(cstate);
            comb[b][g * 64 + m] = h;     // own slice locally for next phase A
            float* dst = Hbuf + ((((size_t)(t & 1)) * 64 + bg) * 4 + b) * 256 + g * 64 + m;
            __hip_atomic_store(dst, h, __ATOMIC_RELAXED, SCOPE_AGENT);
        }
        comb[j >> 6][Hsz + m] = xv;      // x(t+1); x(t) fully consumed in phase A/B
        __syncthreads();                  // implies vmcnt(0) drain per wave before barrier
        if (j == 0)
            __hip_atomic_fetch_add(mycnt, 1, __ATOMIC_RELEASE, SCOPE_AGENT);
    }

    // ---- final projection: wg g==0 of each batch group gathers h(T) and emits out ----
    if (g == 0) {
        if (j == 0) {
            int it = 0;
            while (__hip_atomic_load(mycnt, __ATOMIC_ACQUIRE, SCOPE_AGENT) < 4 * Tsz
                   && it++ < SPIN_CAP)
                __builtin_amdgcn_s_sleep(8);
        }
        __syncthreads();
        {
            const int b = j >> 6;
            if ((m >> 4) != 0) {
                const float* src = Hbuf + ((((size_t)((Tsz - 1) & 1)) * 64 + bg) * 4 + b) * 256;
                const int col = 4 * m;
                const float a0 = __hip_atomic_load(src + col + 0, __ATOMIC_RELAXED, SCOPE_AGENT);
                const float a1 = __hip_atomic_load(src + col + 1, __ATOMIC_RELAXED, SCOPE_AGENT);
                const float a2 = __hip_atomic_load(src + col + 2, __ATOMIC_RELAXED, SCOPE_AGENT);
                const float a3 = __hip_atomic_load(src + col + 3, __ATOMIC_RELAXED, SCOPE_AGENT);
                comb[b][col + 0] = a0; comb[b][col + 1] = a1;
                comb[b][col + 2] = a2; comb[b][col + 3] = a3;
            }
        }
        __syncthreads();
        if (j < NB * Osz) {
            const int b = j >> 3, o = j & 7;
            float s = b_ho[o];
            #pragma unroll 8
            for (int k2 = 0; k2 < Hsz; ++k2)
                s = fmaf(comb[b][k2], W_ho[k2 * Osz + o], s);
            out[(size_t)(b0 + b) * Osz + o] = s;
        }
    }
}

extern "C" void kernel_launch(void* const* d_in, const int* in_sizes, int n_in,
                              void* d_out, int out_size, void* d_ws, size_t ws_size,
                              hipStream_t stream) {
    const float* xp  = (const float*)d_in[0];
    const float* wf  = (const float*)d_in[1];
    const float* bf  = (const float*)d_in[2];
    const float* wi  = (const float*)d_in[3];
    const float* bi  = (const float*)d_in[4];
    const float* wc  = (const float*)d_in[5];
    const float* bc  = (const float*)d_in[6];
    const float* wo  = (const float*)d_in[7];
    const float* bo  = (const float*)d_in[8];
    const float* who = (const float*)d_in[9];
    const float* bho = (const float*)d_in[10];
    float* outp = (float*)d_out;

    int*   cntp  = (int*)d_ws;                       // 64 counters
    float* hbufp = (float*)((char*)d_ws + 4096);     // 2 x 64 x 4 x 256 fp32 = 512 KB

    hipMemsetAsync(d_ws, 0, 4096, stream);           // zero flags (ws re-poisoned each launch)

    // Regular launch: __launch_bounds__(256,1) -> 1 block/CU; 256 blocks on 256 CUs
    // are all co-resident by construction (no block retires until all do).
    lstm_ws_kernel<<<dim3(NG * 64), dim3(256), 0, stream>>>(
        xp, wf, bf, wi, bi, wc, bc, wo, bo, who, bho, outp, cntp, hbufp);
}

// Round 5
// 35825.012 us; speedup vs baseline: 1.2410x; 1.2410x over previous
//
#include <hip/hip_runtime.h>
#include <math.h>

constexpr int Bsz = 256, Tsz = 1024, Isz = 64, Hsz = 256, Osz = 8;
constexpr int NB = 4;     // batch rows per group
constexpr int NG = 4;     // column-split wgs per batch group
constexpr int K  = Hsz + Isz;   // 320
constexpr int WR_OTHR = 48;     // "other-slice" weight rows kept in VGPRs
constexpr int WR_LDS  = 144;    // "other-slice" weight rows kept in LDS (rows 48..191)
constexpr int SPIN_CAP = 1 << 16;   // bounded spin: wrong-fast beats hang

#define SCOPE_AGENT __HIP_MEMORY_SCOPE_AGENT

// FMA over one float4 of comb against 4 weight regs
#define FMA4(vv, warr, base)                      \
  acc[b] = fmaf(vv.x, warr[(base)+0], acc[b]);    \
  acc[b] = fmaf(vv.y, warr[(base)+1], acc[b]);    \
  acc[b] = fmaf(vv.z, warr[(base)+2], acc[b]);    \
  acc[b] = fmaf(vv.w, warr[(base)+3], acc[b]);

__global__ __launch_bounds__(256, 1) void lstm_ws_kernel(
    const float* __restrict__ x,
    const float* __restrict__ W_f, const float* __restrict__ b_f,
    const float* __restrict__ W_i, const float* __restrict__ b_i,
    const float* __restrict__ W_c, const float* __restrict__ b_c,
    const float* __restrict__ W_o, const float* __restrict__ b_o,
    const float* __restrict__ W_ho, const float* __restrict__ b_ho,
    float* __restrict__ out, int* __restrict__ cnt, float* __restrict__ Hbuf)
{
    __shared__ __align__(16) float comb[NB][K];   // [h(256) | x(64)] per batch row, 5120 B
    __shared__ float gat[4][NB][64];              // gate exchange within wg, 4096 B
    __shared__ float Wlds[WR_LDS][256];           // LDS-resident weight rows, 147456 B

    const int j  = threadIdx.x;
    const int g  = blockIdx.x >> 6;     // column-group 0..3
    const int bg = blockIdx.x & 63;     // batch-group 0..63
    const int b0 = bg * NB;
    const int q  = j >> 6;              // gate index (f,i,c,o)
    const int m  = j & 63;              // col within my 64-col h slice
    const int hcol = g * 64 + m;        // column of W_q this thread owns

    const float* Wq  = (q == 0) ? W_f : (q == 1) ? W_i : (q == 2) ? W_c : W_o;
    const float* bqp = (q == 0) ? b_f : (q == 1) ? b_i : (q == 2) ? b_c : b_o;
    const float bias = bqp[hcol];

    // ---- weight-stationary preload: 176 rows in VGPRs, 144 rows in LDS ----
    // row order for the "other three" slices: o in [0,192), krow(o) = ((g+1+(o>>6))&3)*64 + (o&63)
    float wOwn[64], wX[64], wOthR[WR_OTHR];
    #pragma unroll
    for (int kk = 0; kk < 64; ++kk) wOwn[kk] = Wq[(g * 64 + kk) * Hsz + hcol];
    #pragma unroll
    for (int kk = 0; kk < 64; ++kk) wX[kk] = Wq[(Hsz + kk) * Hsz + hcol];
    #pragma unroll
    for (int o = 0; o < WR_OTHR; ++o)   // o>>6 == 0 here -> slice (g+1)&3, rows 0..47
        wOthR[o] = Wq[((((g + 1) & 3) * 64) + o) * Hsz + hcol];
    for (int o = WR_OTHR; o < 192; ++o) // rows 48..191 of the rotated order -> LDS
        Wlds[o - WR_OTHR][j] = Wq[((((g + 1 + (o >> 6)) & 3) * 64) + (o & 63)) * Hsz + hcol];

    // ---- init: h(-1)=0, stage x(0) ----
    #pragma unroll
    for (int b = 0; b < NB; ++b) comb[b][j] = 0.0f;          // cols 0..255
    comb[j >> 6][Hsz + m] = x[((size_t)(b0 + (j >> 6)) * Tsz + 0) * Isz + m];
    float cstate = 0.0f;    // c for (b=j>>6, col g*64+m)
    __syncthreads();

    int* mycnt = cnt + bg;

    for (int t = 0; t < Tsz; ++t) {
        float acc[NB];
        #pragma unroll
        for (int b = 0; b < NB; ++b) acc[b] = bias;

        // ---- phase A: locally-known k ranges (own h slice + x) — before the spin ----
        const int ob = g * 64;
        #pragma unroll
        for (int c4 = 0; c4 < 16; ++c4) {
            #pragma unroll
            for (int b = 0; b < NB; ++b) {
                const float4 v = *(const float4*)&comb[b][ob + c4 * 4];
                FMA4(v, wOwn, c4 * 4)
            }
        }
        #pragma unroll
        for (int c4 = 0; c4 < 16; ++c4) {
            #pragma unroll
            for (int b = 0; b < NB; ++b) {
                const float4 v = *(const float4*)&comb[b][Hsz + c4 * 4];
                FMA4(v, wX, c4 * 4)
            }
        }

        // ---- wait for peers' h(t-1) (ACQUIRE invalidates stale caches), refill 192 cols ----
        if (t) {
            if (j == 0) {
                int it = 0;
                while (__hip_atomic_load(mycnt, __ATOMIC_ACQUIRE, SCOPE_AGENT) < 4 * t
                       && it++ < SPIN_CAP)
                    __builtin_amdgcn_s_sleep(1);
            }
            __syncthreads();
            {
                const int b = j >> 6;
                if ((m >> 4) != g) {     // skip own slice (already in comb)
                    const float* src = Hbuf + ((((size_t)((t - 1) & 1)) * 64 + bg) * 4 + b) * 256;
                    const int col = 4 * m;
                    const float a0 = __hip_atomic_load(src + col + 0, __ATOMIC_RELAXED, SCOPE_AGENT);
                    const float a1 = __hip_atomic_load(src + col + 1, __ATOMIC_RELAXED, SCOPE_AGENT);
                    const float a2 = __hip_atomic_load(src + col + 2, __ATOMIC_RELAXED, SCOPE_AGENT);
                    const float a3 = __hip_atomic_load(src + col + 3, __ATOMIC_RELAXED, SCOPE_AGENT);
                    comb[b][col + 0] = a0; comb[b][col + 1] = a1;
                    comb[b][col + 2] = a2; comb[b][col + 3] = a3;
                }
            }
            __syncthreads();
        }

        // ---- phase B: the other 3 h-slices; first 48 rows from VGPR, 144 from LDS ----
        const int kb1 = ((g + 1) & 3) * 64;
        #pragma unroll
        for (int oc = 0; oc < WR_OTHR; oc += 4) {
            #pragma unroll
            for (int b = 0; b < NB; ++b) {
                const float4 v = *(const float4*)&comb[b][kb1 + oc];
                FMA4(v, wOthR, oc)
            }
        }
        #pragma unroll
        for (int oc = WR_OTHR; oc < 192; oc += 4) {
            const float w0 = Wlds[oc - WR_OTHR + 0][j];
            const float w1 = Wlds[oc - WR_OTHR + 1][j];
            const float w2 = Wlds[oc - WR_OTHR + 2][j];
            const float w3 = Wlds[oc - WR_OTHR + 3][j];
            const int k = ((g + 1 + (oc >> 6)) & 3) * 64 + (oc & 63);
            #pragma unroll
            for (int b = 0; b < NB; ++b) {
                const float4 v = *(const float4*)&comb[b][k];
                acc[b] = fmaf(v.x, w0, acc[b]);
                acc[b] = fmaf(v.y, w1, acc[b]);
                acc[b] = fmaf(v.z, w2, acc[b]);
                acc[b] = fmaf(v.w, w3, acc[b]);
            }
        }

        // ---- prefetch x(t+1) (consumed after the final barrier) ----
        float xv;
        {
            const int tt = (t + 1 < Tsz) ? t + 1 : t;
            xv = x[((size_t)(b0 + (j >> 6)) * Tsz + tt) * Isz + m];
        }

        // ---- gate exchange + cell update ----
        #pragma unroll
        for (int b = 0; b < NB; ++b) gat[q][b][m] = acc[b];
        __syncthreads();
        {
            const int b = j >> 6;
            const float gf = gat[0][b][m], gi = gat[1][b][m];
            const float gc = gat[2][b][m], go = gat[3][b][m];
            const float f  = 1.0f / (1.0f + expf(-gf));
            const float ii = 1.0f / (1.0f + expf(-gi));
            const float ch = tanhf(gc);
            const float oo = 1.0f / (1.0f + expf(-go));
            cstate = f * cstate + ii * ch;
            const float h = oo * tanhf(cstate);
            comb[b][g * 64 + m] = h;     // own slice locally for next phase A
            float* dst = Hbuf + ((((size_t)(t & 1)) * 64 + bg) * 4 + b) * 256 + g * 64 + m;
            __hip_atomic_store(dst, h, __ATOMIC_RELAXED, SCOPE_AGENT);
        }
        comb[j >> 6][Hsz + m] = xv;      // x(t+1); x(t) fully consumed in phase A/B
        __syncthreads();                  // wave-level vmcnt(0) drain precedes barrier
        if (j == 0)
            __hip_atomic_fetch_add(mycnt, 1, __ATOMIC_RELEASE, SCOPE_AGENT);
    }

    // ---- final projection: wg g==0 of each batch group gathers h(T) and emits out ----
    if (g == 0) {
        if (j == 0) {
            int it = 0;
            while (__hip_atomic_load(mycnt, __ATOMIC_ACQUIRE, SCOPE_AGENT) < 4 * Tsz
                   && it++ < SPIN_CAP)
                __builtin_amdgcn_s_sleep(1);
        }
        __syncthreads();
        {
            const int b = j >> 6;
            if ((m >> 4) != 0) {
                const float* src = Hbuf + ((((size_t)((Tsz - 1) & 1)) * 64 + bg) * 4 + b) * 256;
                const int col = 4 * m;
                const float a0 = __hip_atomic_load(src + col + 0, __ATOMIC_RELAXED, SCOPE_AGENT);
                const float a1 = __hip_atomic_load(src + col + 1, __ATOMIC_RELAXED, SCOPE_AGENT);
                const float a2 = __hip_atomic_load(src + col + 2, __ATOMIC_RELAXED, SCOPE_AGENT);
                const float a3 = __hip_atomic_load(src + col + 3, __ATOMIC_RELAXED, SCOPE_AGENT);
                comb[b][col + 0] = a0; comb[b][col + 1] = a1;
                comb[b][col + 2] = a2; comb[b][col + 3] = a3;
            }
        }
        __syncthreads();
        if (j < NB * Osz) {
            const int b = j >> 3, o = j & 7;
            float s = b_ho[o];
            #pragma unroll 8
            for (int k2 = 0; k2 < Hsz; ++k2)
                s = fmaf(comb[b][k2], W_ho[k2 * Osz + o], s);
            out[(size_t)(b0 + b) * Osz + o] = s;
        }
    }
}

extern "C" void kernel_launch(void* const* d_in, const int* in_sizes, int n_in,
                              void* d_out, int out_size, void* d_ws, size_t ws_size,
                              hipStream_t stream) {
    const float* xp  = (const float*)d_in[0];
    const float* wf  = (const float*)d_in[1];
    const float* bf  = (const float*)d_in[2];
    const float* wi  = (const float*)d_in[3];
    const float* bi  = (const float*)d_in[4];
    const float* wc  = (const float*)d_in[5];
    const float* bc  = (const float*)d_in[6];
    const float* wo  = (const float*)d_in[7];
    const float* bo  = (const float*)d_in[8];
    const float* who = (const float*)d_in[9];
    const float* bho = (const float*)d_in[10];
    float* outp = (float*)d_out;

    int*   cntp  = (int*)d_ws;                       // 64 counters
    float* hbufp = (float*)((char*)d_ws + 4096);     // 2 x 64 x 4 x 256 fp32 = 512 KB

    hipMemsetAsync(d_ws, 0, 4096, stream);           // zero flags (ws re-poisoned each launch)

    // Regular launch: __launch_bounds__(256,1) -> 1 block/CU; 256 blocks on 256 CUs
    // are all co-resident by construction (no block retires until all do).
    lstm_ws_kernel<<<dim3(NG * 64), dim3(256), 0, stream>>>(
        xp, wf, bf, wi, bi, wc, bc, wo, bo, who, bho, outp, cntp, hbufp);
}